// Round 7
// baseline (549.178 us; speedup 1.0000x reference)
//
#include <hip/hip_runtime.h>
#include <cstdint>
#include <cmath>

#define RLN2 1.44269504088896340736f

typedef __attribute__((ext_vector_type(8))) short short8;
typedef __attribute__((ext_vector_type(4))) short short4v;
typedef __attribute__((ext_vector_type(4))) float f32x4;
typedef __attribute__((ext_vector_type(16))) float f32x16;
typedef __attribute__((ext_vector_type(4))) unsigned int uint4v;

__device__ __forceinline__ unsigned short f2bf(float f) {
  unsigned int u = __float_as_uint(f);
  u += 0x7fffu + ((u >> 16) & 1u);
  return (unsigned short)(u >> 16);
}

__device__ __forceinline__ unsigned int cvt_pk_bf16(float lo, float hi) {
  unsigned int r;
  asm("v_cvt_pk_bf16_f32 %0, %1, %2" : "=v"(r) : "v"(lo), "v"(hi));
  return r;
}

__device__ __forceinline__ float fast_exp2(float x) {
#if __has_builtin(__builtin_amdgcn_exp2f)
  return __builtin_amdgcn_exp2f(x);
#else
  return exp2f(x);
#endif
}

__device__ __forceinline__ void gload16(const void* g, void* l) {
  __builtin_amdgcn_global_load_lds(
      (const __attribute__((address_space(1))) unsigned int*)g,
      (__attribute__((address_space(3))) unsigned int*)l,
      16, 0, 0);
}

// ---------------- fp32 -> bf16 conversions ----------------

__global__ void __launch_bounds__(256) k_cvt_hs(const float* __restrict__ src,
                                                unsigned short* __restrict__ dst) {
  size_t i = (size_t)blockIdx.x * 256 + threadIdx.x;
  const float4* s = (const float4*)src + i * 2;
  float4 a = s[0], b = s[1];
  short8 o;
  o[0] = (short)f2bf(a.x); o[1] = (short)f2bf(a.y); o[2] = (short)f2bf(a.z); o[3] = (short)f2bf(a.w);
  o[4] = (short)f2bf(b.x); o[5] = (short)f2bf(b.y); o[6] = (short)f2bf(b.z); o[7] = (short)f2bf(b.w);
  ((short8*)dst)[i] = o;
}

__global__ void __launch_bounds__(256) k_cvt_w(const float* __restrict__ Wq,
                                               const float* __restrict__ Wk,
                                               const float* __restrict__ Wv,
                                               unsigned short* __restrict__ dst) {
  size_t i = (size_t)blockIdx.x * 256 + threadIdx.x;
  int e = (int)(i * 8);
  int n = e >> 10, c = e & 1023;
  const float* row = (n < 1024) ? (Wq + (size_t)n * 1024)
                   : (n < 2048) ? (Wk + (size_t)(n - 1024) * 1024)
                                : (Wv + (size_t)(n - 2048) * 1024);
  const float4* s = (const float4*)(row + c);
  float4 a = s[0], b = s[1];
  short8 o;
  o[0] = (short)f2bf(a.x); o[1] = (short)f2bf(a.y); o[2] = (short)f2bf(a.z); o[3] = (short)f2bf(a.w);
  o[4] = (short)f2bf(b.x); o[5] = (short)f2bf(b.y); o[6] = (short)f2bf(b.z); o[7] = (short)f2bf(b.w);
  ((short8*)dst)[i] = o;
}

__global__ void __launch_bounds__(256) k_seg(const int* __restrict__ seg_ids,
                                             const float* __restrict__ seg_table,
                                             unsigned short* __restrict__ Kaug) {
  size_t i = (size_t)blockIdx.x * 256 + threadIdx.x;
  int e = (int)(i * 8);
  int jl = e >> 10;
  int r  = e & 1023;
  int sid = seg_ids[jl];
  const float4* s = (const float4*)(seg_table + (size_t)sid * 1024 + r);
  float4 a = s[0], b = s[1];
  short8 o;
  o[0] = (short)f2bf(a.x); o[1] = (short)f2bf(a.y); o[2] = (short)f2bf(a.z); o[3] = (short)f2bf(a.w);
  o[4] = (short)f2bf(b.x); o[5] = (short)f2bf(b.y); o[6] = (short)f2bf(b.z); o[7] = (short)f2bf(b.w);
  int b_ = jl >> 11, j = jl & 2047;
  int h = r >> 6, d = r & 63;
  size_t off = ((size_t)(b_ * 16 + h) * 2048 + j) * 128 + 64 + d;
  *(short8*)(Kaug + off) = o;
}

// ---------------- fused QKV GEMM (NT) ----------------
// epilogue: Q -> Qaug (scaled halves), K -> Kaug first half,
// V -> Vb: k-blocked coalesced layout [bh][jblk=S/16][dv 64][kk 16] (elems),
// with the PV k-permutation folded in:
//   k = sdx&63 = m*16 + g*4 + r  ->  jblk = (sdx>>6)*4 + 2*((m>>1)&1) + (m&1),
//   kk = 8*(g&1) + 4*((g>>1)&1) + r   (r consecutive -> one 8B store)
__global__ void __launch_bounds__(256) k_gemm(const unsigned short* __restrict__ A,
                                              const unsigned short* __restrict__ Bw,
                                              const float* __restrict__ bq,
                                              const float* __restrict__ bv,
                                              const float* __restrict__ bqs,
                                              unsigned short* __restrict__ Qaug,
                                              unsigned short* __restrict__ Kaug,
                                              unsigned short* __restrict__ Vb) {
  __shared__ unsigned short As[128 * 32];
  __shared__ unsigned short Bs[128 * 32];
  int n0 = blockIdx.x * 128;
  int m0 = blockIdx.y * 128;
  int tid = threadIdx.x;
  int w = tid >> 6, lane = tid & 63;
  int wr = (w >> 1) * 64, wc = (w & 1) * 64;
  int rA = lane & 15;
  int kg = (lane >> 4) * 16;
  f32x4 acc[4][4] = {};
  const char* Ab = (const char*)A;
  const char* Bb = (const char*)Bw;

  for (int kt = 0; kt < 32; ++kt) {
    int kb0 = kt * 64;
#pragma unroll
    for (int c = 0; c < 2; ++c) {
      int chunk = w * 2 + c;
      int y = chunk * 1024 + lane * 16;
      int row = y >> 6, colb = y & 63;
      gload16(Ab + (size_t)(m0 + row) * 2048 + kb0 + colb, (char*)As + chunk * 1024);
      gload16(Bb + (size_t)(n0 + row) * 2048 + kb0 + colb, (char*)Bs + chunk * 1024);
    }
    __syncthreads();
    short8 af[4], bfr[4];
#pragma unroll
    for (int m = 0; m < 4; ++m)
      af[m] = *(const short8*)((const char*)As + (wr + m * 16 + rA) * 64 + kg);
#pragma unroll
    for (int n = 0; n < 4; ++n)
      bfr[n] = *(const short8*)((const char*)Bs + (wc + n * 16 + rA) * 64 + kg);
#pragma unroll
    for (int m = 0; m < 4; ++m)
#pragma unroll
      for (int n = 0; n < 4; ++n)
        acc[m][n] = __builtin_amdgcn_mfma_f32_16x16x32_bf16(af[m], bfr[n], acc[m][n], 0, 0, 0);
    __syncthreads();
  }

  int seg = n0 >> 10;
  int colbase = n0 & 1023;
  int g = lane >> 4;
#pragma unroll
  for (int n = 0; n < 4; ++n) {
    int o = colbase + wc + n * 16 + (lane & 15);
    int h = o >> 6, d = o & 63;
    float bias = 0.f, bqsv = 0.f;
    if (seg == 0) { bias = bq[o]; bqsv = bqs[o]; }
    else if (seg == 2) { bias = bv[o]; }
#pragma unroll
    for (int m = 0; m < 4; ++m) {
      if (seg == 2) {
        int i = m0 + wr + m * 16 + g * 4;  // r=0 token
        int b_ = i >> 11, sdx = i & 2047;
        int bh = b_ * 16 + h;
        int jblk = (sdx >> 6) * 4 + 2 * ((m >> 1) & 1) + (m & 1);
        int kk = 8 * (g & 1) + 4 * ((g >> 1) & 1);
        short4v pv;
#pragma unroll
        for (int r = 0; r < 4; ++r)
          pv[r] = (short)f2bf(acc[m][n][r] + bias);
        *(short4v*)(Vb + (size_t)bh * 131072 + jblk * 1024 + d * 16 + kk) = pv;
      } else {
#pragma unroll
        for (int r = 0; r < 4; ++r) {
          int i = m0 + wr + m * 16 + g * 4 + r;
          int b_ = i >> 11, sdx = i & 2047;
          float val = acc[m][n][r];
          size_t tok = (size_t)(b_ * 16 + h) * 2048 + sdx;
          if (seg == 0) {
            float qv = val + bias;
            Qaug[tok * 128 + d]      = f2bf(qv * (0.125f * RLN2));
            Qaug[tok * 128 + 64 + d] = f2bf((qv + bqsv) * RLN2);
          } else {
            Kaug[tok * 128 + d] = f2bf(val);
          }
        }
      }
    }
  }
}

// ---------------- flash attention, 32x32x16 MFMA, 32 q-rows/wave ----------------
// R3 structure + grid order (proven), with V moved out of LDS into REGISTERS:
// 8 coalesced 1KB global loads per wave per tile (k-blocked Vb layout), issued at
// tile start (T14 issue-early), consumed by PV ~2000 cycles later. LDS holds only
// the K double buffer (32KB). Per-wave LDS reads/tile: 24 -> 16.
__global__ void __launch_bounds__(256, 3) k_attn(const unsigned short* __restrict__ Qaug,
                                                 const unsigned short* __restrict__ Kaug,
                                                 const unsigned short* __restrict__ Vb,
                                                 const float* __restrict__ mask,
                                                 float* __restrict__ out) {
  __shared__ char smem[32768];
  char* Ksb = smem;  // 2 x 16K

  int qt = blockIdx.x, h = blockIdx.y, b_ = blockIdx.z;
  int bh = b_ * 16 + h;
  int i0 = qt * 128;
  int tid = threadIdx.x, w = tid >> 6, lane = tid & 63;
  int q = lane & 31, hi = lane >> 5;
  int swzq = (q & 7) << 4;
  const char* Qg = (const char*)Qaug + (size_t)bh * 2048 * 256;
  const char* Kg = (const char*)Kaug + (size_t)bh * 2048 * 256;
  const char* Vbg = (const char*)Vb + (size_t)bh * 262144;
  const float* maskb = mask + (size_t)b_ * 2048;

  // tile-invariant K fragment byte offsets (within a K row)
  int foff[8];
#pragma unroll
  for (int ds = 0; ds < 8; ++ds)
    foff[ds] = (ds * 32 + hi * 16) ^ swzq;

  // per-lane V base: dv = lane&31 (+32 via +1024B), kk-half = hi
  const char* vbl = Vbg + (lane & 31) * 32 + hi * 16;

  // K staging lane decomp
  int kst_row = lane >> 4, kst_x = (lane & 15) * 16;

  // ---- stage K tile 0 ----
#pragma unroll
  for (int c = 0; c < 4; ++c) {
    int ck = w * 4 + c;
    int krow = ck * 4 + kst_row;
    gload16(Kg + (size_t)krow * 256 + (kst_x ^ ((krow & 7) << 4)), Ksb + ck * 1024);
  }

  // Q fragments (B-operand): row = i0 + w*32 + q, 8 x 16B at ds*32 + hi*16
  short8 qf[8];
  {
    const char* qrow = Qg + (size_t)(i0 + w * 32 + q) * 256 + hi * 16;
#pragma unroll
    for (int ds = 0; ds < 8; ++ds)
      qf[ds] = *(const short8*)(qrow + ds * 32);
  }
  __syncthreads();  // K0 resident

  float m_run = -1e30f, l_run = 0.f;
  f32x16 accO[2] = {};

  for (int t = 0; t < 32; ++t) {
    int cur = t & 1, nxt = cur ^ 1;
    int j0 = t * 64;

    // ---- issue V loads for THIS tile first (coalesced 1KB each, L2/L3) ----
    const char* vbp = vbl + t * 8192;
    short8 vf[8];
#pragma unroll
    for (int ks = 0; ks < 4; ++ks) {
      vf[2 * ks]     = *(const short8*)(vbp + ks * 2048);
      vf[2 * ks + 1] = *(const short8*)(vbp + ks * 2048 + 1024);
    }

    // ---- issue next K tile staging ----
    if (t < 31) {
      int jn = j0 + 64;
      char* kd = Ksb + nxt * 16384;
#pragma unroll
      for (int c = 0; c < 4; ++c) {
        int ck = w * 4 + c;
        int krow = ck * 4 + kst_row;
        gload16(Kg + (size_t)(jn + krow) * 256 + (kst_x ^ ((krow & 7) << 4)), kd + ck * 1024);
      }
    }
    __builtin_amdgcn_sched_barrier(0);  // keep all loads issued before compute

    const char* kq = Ksb + cur * 16384 + q * 256;

    // ---- S^T = K . Q^T (two 32x32 k-halves, 8 d-steps) ----
    f32x16 s0 = {}, s1 = {};
    __builtin_amdgcn_s_setprio(1);
#pragma unroll
    for (int ds = 0; ds < 8; ++ds) {
      short8 kf0 = *(const short8*)(kq + foff[ds]);
      short8 kf1 = *(const short8*)(kq + foff[ds] + 8192);
      s0 = __builtin_amdgcn_mfma_f32_32x32x16_bf16(kf0, qf[ds], s0, 0, 0, 0);
      s1 = __builtin_amdgcn_mfma_f32_32x32x16_bf16(kf1, qf[ds], s1, 0, 0, 0);
    }
    __builtin_amdgcn_s_setprio(0);

    // ---- mask add: s*[4c+r] is k = kh*32 + 4*hi + r + 8*c ----
#pragma unroll
    for (int c = 0; c < 4; ++c) {
      f32x4 mv0 = *(const f32x4*)(maskb + j0 + 8 * c + 4 * hi);
      f32x4 mv1 = *(const f32x4*)(maskb + j0 + 32 + 8 * c + 4 * hi);
#pragma unroll
      for (int r = 0; r < 4; ++r) {
        s0[4 * c + r] += mv0[r] * RLN2;
        s1[4 * c + r] += mv1[r] * RLN2;
      }
    }

    // ---- online softmax: lane owns q; reduce across hi via xor 32 ----
    float tm = -1e30f;
#pragma unroll
    for (int i = 0; i < 16; ++i) tm = fmaxf(tm, fmaxf(s0[i], s1[i]));
    tm = fmaxf(tm, __shfl_xor(tm, 32));

    if (__any(tm > m_run + 8.0f)) {  // defer-max (T13)
      float mn = fmaxf(m_run, tm);
      float alpha = fast_exp2(m_run - mn);
      m_run = mn;
      l_run *= alpha;
#pragma unroll
      for (int i = 0; i < 16; ++i) { accO[0][i] *= alpha; accO[1][i] *= alpha; }
    }

    float ps = 0.f;
#pragma unroll
    for (int i = 0; i < 16; ++i) {
      float e0 = fast_exp2(s0[i] - m_run);
      float e1 = fast_exp2(s1[i] - m_run);
      s0[i] = e0; s1[i] = e1;
      ps += e0 + e1;
    }
    ps += __shfl_xor(ps, 32);
    l_run += ps;

    // ---- O += V . P : V fragments already in registers ----
    __builtin_amdgcn_s_setprio(1);
#pragma unroll
    for (int ks = 0; ks < 4; ++ks) {
      int o = 8 * (ks & 1);
      const f32x16& sv = (ks < 2) ? s0 : s1;
      uint4v pa;
      pa[0] = cvt_pk_bf16(sv[o + 0], sv[o + 1]);
      pa[1] = cvt_pk_bf16(sv[o + 2], sv[o + 3]);
      pa[2] = cvt_pk_bf16(sv[o + 4], sv[o + 5]);
      pa[3] = cvt_pk_bf16(sv[o + 6], sv[o + 7]);
      short8 pf = __builtin_bit_cast(short8, pa);
      accO[0] = __builtin_amdgcn_mfma_f32_32x32x16_bf16(vf[2 * ks],     pf, accO[0], 0, 0, 0);
      accO[1] = __builtin_amdgcn_mfma_f32_32x32x16_bf16(vf[2 * ks + 1], pf, accO[1], 0, 0, 0);
    }
    __builtin_amdgcn_s_setprio(0);
    __syncthreads();  // next K tile staged; buffers swap
  }

  float inv = 1.0f / l_run;
  float* orow = out + ((size_t)b_ * 2048 + i0 + w * 32 + q) * 1024 + h * 64;
#pragma unroll
  for (int vh = 0; vh < 2; ++vh) {
#pragma unroll
    for (int c = 0; c < 4; ++c) {
      f32x4 o;
      o[0] = accO[vh][4 * c + 0] * inv;
      o[1] = accO[vh][4 * c + 1] * inv;
      o[2] = accO[vh][4 * c + 2] * inv;
      o[3] = accO[vh][4 * c + 3] * inv;
      *(f32x4*)(orow + vh * 32 + 8 * c + 4 * hi) = o;
    }
  }
}

extern "C" void kernel_launch(void* const* d_in, const int* in_sizes, int n_in,
                              void* d_out, int out_size, void* d_ws, size_t ws_size,
                              hipStream_t stream) {
  (void)in_sizes; (void)n_in; (void)out_size; (void)ws_size;
  const float* hs        = (const float*)d_in[0];
  const float* mask      = (const float*)d_in[1];
  const int*   seg_ids   = (const int*)d_in[2];
  const float* Wq        = (const float*)d_in[3];
  const float* bq        = (const float*)d_in[4];
  const float* Wk        = (const float*)d_in[5];
  const float* Wv        = (const float*)d_in[6];
  const float* bv        = (const float*)d_in[7];
  const float* seg_table = (const float*)d_in[8];
  const float* bqs       = (const float*)d_in[9];
  float* out = (float*)d_out;
  char* ws = (char*)d_ws;

  unsigned short* hsb  = (unsigned short*)(ws + 0);         // 16 MiB
  unsigned short* Wcat = (unsigned short*)(ws + 16777216);  // 6 MiB
  unsigned short* Qaug = (unsigned short*)(ws + 23068672);  // 32 MiB
  unsigned short* Kaug = (unsigned short*)(ws + 56623104);  // 32 MiB
  unsigned short* Vb   = (unsigned short*)(ws + 90177536);  // 16 MiB (k-blocked, from gemm)

  k_cvt_hs<<<dim3(4096), dim3(256), 0, stream>>>(hs, hsb);
  k_cvt_w<<<dim3(1536), dim3(256), 0, stream>>>(Wq, Wk, Wv, Wcat);
  k_gemm<<<dim3(24, 64), dim3(256), 0, stream>>>(hsb, Wcat, bq, bv, bqs, Qaug, Kaug, Vb);
  k_seg<<<dim3(4096), dim3(256), 0, stream>>>(seg_ids, seg_table, Kaug);
  k_attn<<<dim3(16, 16, 4), dim3(256), 0, stream>>>(Qaug, Kaug, Vb, mask, out);
}

// Round 8
// 333.432 us; speedup vs baseline: 1.6470x; 1.6470x over previous
//
#include <hip/hip_runtime.h>
#include <cstdint>
#include <cmath>

#define RLN2 1.44269504088896340736f

typedef __attribute__((ext_vector_type(8))) short short8;
typedef __attribute__((ext_vector_type(4))) short short4v;
typedef __attribute__((ext_vector_type(4))) float f32x4;
typedef __attribute__((ext_vector_type(16))) float f32x16;
typedef __attribute__((ext_vector_type(4))) unsigned int uint4v;

__device__ __forceinline__ unsigned short f2bf(float f) {
  unsigned int u = __float_as_uint(f);
  u += 0x7fffu + ((u >> 16) & 1u);
  return (unsigned short)(u >> 16);
}

__device__ __forceinline__ unsigned int cvt_pk_bf16(float lo, float hi) {
  unsigned int r;
  asm("v_cvt_pk_bf16_f32 %0, %1, %2" : "=v"(r) : "v"(lo), "v"(hi));
  return r;
}

__device__ __forceinline__ float fast_exp2(float x) {
#if __has_builtin(__builtin_amdgcn_exp2f)
  return __builtin_amdgcn_exp2f(x);
#else
  return exp2f(x);
#endif
}

__device__ __forceinline__ void gload16(const void* g, void* l) {
  __builtin_amdgcn_global_load_lds(
      (const __attribute__((address_space(1))) unsigned int*)g,
      (__attribute__((address_space(3))) unsigned int*)l,
      16, 0, 0);
}

// ---------------- fp32 -> bf16 conversions ----------------

__global__ void __launch_bounds__(256) k_cvt_hs(const float* __restrict__ src,
                                                unsigned short* __restrict__ dst) {
  size_t i = (size_t)blockIdx.x * 256 + threadIdx.x;
  const float4* s = (const float4*)src + i * 2;
  float4 a = s[0], b = s[1];
  short8 o;
  o[0] = (short)f2bf(a.x); o[1] = (short)f2bf(a.y); o[2] = (short)f2bf(a.z); o[3] = (short)f2bf(a.w);
  o[4] = (short)f2bf(b.x); o[5] = (short)f2bf(b.y); o[6] = (short)f2bf(b.z); o[7] = (short)f2bf(b.w);
  ((short8*)dst)[i] = o;
}

__global__ void __launch_bounds__(256) k_cvt_w(const float* __restrict__ Wq,
                                               const float* __restrict__ Wk,
                                               const float* __restrict__ Wv,
                                               unsigned short* __restrict__ dst) {
  size_t i = (size_t)blockIdx.x * 256 + threadIdx.x;
  int e = (int)(i * 8);
  int n = e >> 10, c = e & 1023;
  const float* row = (n < 1024) ? (Wq + (size_t)n * 1024)
                   : (n < 2048) ? (Wk + (size_t)(n - 1024) * 1024)
                                : (Wv + (size_t)(n - 2048) * 1024);
  const float4* s = (const float4*)(row + c);
  float4 a = s[0], b = s[1];
  short8 o;
  o[0] = (short)f2bf(a.x); o[1] = (short)f2bf(a.y); o[2] = (short)f2bf(a.z); o[3] = (short)f2bf(a.w);
  o[4] = (short)f2bf(b.x); o[5] = (short)f2bf(b.y); o[6] = (short)f2bf(b.z); o[7] = (short)f2bf(b.w);
  ((short8*)dst)[i] = o;
}

// fills Kaug second half + precomputes mask2 = mask * RLN2
__global__ void __launch_bounds__(256) k_seg(const int* __restrict__ seg_ids,
                                             const float* __restrict__ seg_table,
                                             const float* __restrict__ mask,
                                             unsigned short* __restrict__ Kaug,
                                             float* __restrict__ mask2) {
  size_t i = (size_t)blockIdx.x * 256 + threadIdx.x;
  int e = (int)(i * 8);
  int jl = e >> 10;
  int r  = e & 1023;
  if (r == 0) mask2[jl] = mask[jl] * RLN2;
  int sid = seg_ids[jl];
  const float4* s = (const float4*)(seg_table + (size_t)sid * 1024 + r);
  float4 a = s[0], b = s[1];
  short8 o;
  o[0] = (short)f2bf(a.x); o[1] = (short)f2bf(a.y); o[2] = (short)f2bf(a.z); o[3] = (short)f2bf(a.w);
  o[4] = (short)f2bf(b.x); o[5] = (short)f2bf(b.y); o[6] = (short)f2bf(b.z); o[7] = (short)f2bf(b.w);
  int b_ = jl >> 11, j = jl & 2047;
  int h = r >> 6, d = r & 63;
  size_t off = ((size_t)(b_ * 16 + h) * 2048 + j) * 128 + 64 + d;
  *(short8*)(Kaug + off) = o;
}

// ---------------- fused QKV GEMM (NT) ----------------
// epilogue: Q -> Qaug (scaled halves), K -> Kaug first half,
// V -> Vt DIRECTLY: [bh][64 dv][2048 pos] with the PV k-permutation folded in:
//   k = sdx&63 = m*16 + g*4 + r -> pos = (sdx&~63) + 32*((m>>1)&1) + 16*(m&1) + 8*(g&1) + 4*((g>>1)&1) + r
__global__ void __launch_bounds__(256) k_gemm(const unsigned short* __restrict__ A,
                                              const unsigned short* __restrict__ Bw,
                                              const float* __restrict__ bq,
                                              const float* __restrict__ bv,
                                              const float* __restrict__ bqs,
                                              unsigned short* __restrict__ Qaug,
                                              unsigned short* __restrict__ Kaug,
                                              unsigned short* __restrict__ Vt) {
  __shared__ unsigned short As[128 * 32];
  __shared__ unsigned short Bs[128 * 32];
  int n0 = blockIdx.x * 128;
  int m0 = blockIdx.y * 128;
  int tid = threadIdx.x;
  int w = tid >> 6, lane = tid & 63;
  int wr = (w >> 1) * 64, wc = (w & 1) * 64;
  int rA = lane & 15;
  int kg = (lane >> 4) * 16;
  f32x4 acc[4][4] = {};
  const char* Ab = (const char*)A;
  const char* Bb = (const char*)Bw;

  for (int kt = 0; kt < 32; ++kt) {
    int kb0 = kt * 64;
#pragma unroll
    for (int c = 0; c < 2; ++c) {
      int chunk = w * 2 + c;
      int y = chunk * 1024 + lane * 16;
      int row = y >> 6, colb = y & 63;
      gload16(Ab + (size_t)(m0 + row) * 2048 + kb0 + colb, (char*)As + chunk * 1024);
      gload16(Bb + (size_t)(n0 + row) * 2048 + kb0 + colb, (char*)Bs + chunk * 1024);
    }
    __syncthreads();
    short8 af[4], bfr[4];
#pragma unroll
    for (int m = 0; m < 4; ++m)
      af[m] = *(const short8*)((const char*)As + (wr + m * 16 + rA) * 64 + kg);
#pragma unroll
    for (int n = 0; n < 4; ++n)
      bfr[n] = *(const short8*)((const char*)Bs + (wc + n * 16 + rA) * 64 + kg);
#pragma unroll
    for (int m = 0; m < 4; ++m)
#pragma unroll
      for (int n = 0; n < 4; ++n)
        acc[m][n] = __builtin_amdgcn_mfma_f32_16x16x32_bf16(af[m], bfr[n], acc[m][n], 0, 0, 0);
    __syncthreads();
  }

  int seg = n0 >> 10;
  int colbase = n0 & 1023;
  int g = lane >> 4;
#pragma unroll
  for (int n = 0; n < 4; ++n) {
    int o = colbase + wc + n * 16 + (lane & 15);
    int h = o >> 6, d = o & 63;
    float bias = 0.f, bqsv = 0.f;
    if (seg == 0) { bias = bq[o]; bqsv = bqs[o]; }
    else if (seg == 2) { bias = bv[o]; }
#pragma unroll
    for (int m = 0; m < 4; ++m) {
      if (seg == 2) {
        int i = m0 + wr + m * 16 + g * 4;  // r=0 token
        int b_ = i >> 11, sdx = i & 2047;
        int bh = b_ * 16 + h;
        int pos = (sdx & ~63) + 32 * ((m >> 1) & 1) + 16 * (m & 1) + 8 * (g & 1) + 4 * ((g >> 1) & 1);
        short4v pv;
#pragma unroll
        for (int r = 0; r < 4; ++r)
          pv[r] = (short)f2bf(acc[m][n][r] + bias);
        *(short4v*)(Vt + (size_t)bh * 131072 + (size_t)d * 2048 + pos) = pv;
      } else {
#pragma unroll
        for (int r = 0; r < 4; ++r) {
          int i = m0 + wr + m * 16 + g * 4 + r;
          int b_ = i >> 11, sdx = i & 2047;
          float val = acc[m][n][r];
          size_t tok = (size_t)(b_ * 16 + h) * 2048 + sdx;
          if (seg == 0) {
            float qv = val + bias;
            Qaug[tok * 128 + d]      = f2bf(qv * (0.125f * RLN2));
            Qaug[tok * 128 + 64 + d] = f2bf((qv + bqsv) * RLN2);
          } else {
            Kaug[tok * 128 + d] = f2bf(val);
          }
        }
      }
    }
  }
}

// ---------------- flash attention, 32x32x16 MFMA, 32 q-rows/wave ----------------
// R3 structure with V SINGLE-buffered (two barriers/tile): LDS 40KB -> 4 blocks/CU
// (16 waves, +33% TLP vs R3; VGPR ~90 fits the 128-slot quantum for 4 waves/SIMD).
// Grid 1024 = fully co-resident, single pass.
__global__ void __launch_bounds__(256, 4) k_attn(const unsigned short* __restrict__ Qaug,
                                                 const unsigned short* __restrict__ Kaug,
                                                 const unsigned short* __restrict__ Vt,
                                                 const float* __restrict__ mask2,
                                                 float* __restrict__ out) {
  __shared__ char smem[40960];
  char* Ksb = smem;          // 2 x 16K (double-buffered K)
  char* Vsb = smem + 32768;  // 8K (single-buffered V)

  int qt = blockIdx.x, h = blockIdx.y, b_ = blockIdx.z;
  int bh = b_ * 16 + h;
  int i0 = qt * 128;
  int tid = threadIdx.x, w = tid >> 6, lane = tid & 63;
  int q = lane & 31, hi = lane >> 5;
  int swzq = (q & 7) << 4;
  const char* Qg = (const char*)Qaug + (size_t)bh * 2048 * 256;
  const char* Kg = (const char*)Kaug + (size_t)bh * 2048 * 256;
  const char* Vg = (const char*)Vt + (size_t)bh * 64 * 4096;
  const float* maskb = mask2 + (size_t)b_ * 2048;

  // tile-invariant fragment byte offsets (within a K row / V row)
  int foff[8];
#pragma unroll
  for (int ds = 0; ds < 8; ++ds)
    foff[ds] = (ds * 32 + hi * 16) ^ swzq;

  // staging lane decomps
  int kst_row = lane >> 4, kst_x = (lane & 15) * 16;
  int vst_dv = lane >> 3;
  int vst_x = ((lane & 7) * 16) ^ ((vst_dv & 7) << 4);

  // ---- prologue: stage K tile 0 and V tile 0 ----
#pragma unroll
  for (int c = 0; c < 4; ++c) {
    int ck = w * 4 + c;
    int krow = ck * 4 + kst_row;
    gload16(Kg + (size_t)krow * 256 + (kst_x ^ ((krow & 7) << 4)), Ksb + ck * 1024);
  }
#pragma unroll
  for (int c = 0; c < 2; ++c) {
    int ck = w * 2 + c;
    int dv = ck * 8 + vst_dv;
    gload16(Vg + (size_t)dv * 4096 + vst_x, Vsb + ck * 1024);
  }

  // Q fragments (B-operand): row = i0 + w*32 + q, 8 x 16B at ds*32 + hi*16
  short8 qf[8];
  {
    const char* qrow = Qg + (size_t)(i0 + w * 32 + q) * 256 + hi * 16;
#pragma unroll
    for (int ds = 0; ds < 8; ++ds)
      qf[ds] = *(const short8*)(qrow + ds * 32);
  }
  __syncthreads();  // K0/V0 resident

  float m_run = -1e30f, l_run = 0.f;
  f32x16 accO[2] = {};

  for (int t = 0; t < 32; ++t) {
    int cur = t & 1, nxt = cur ^ 1;
    int j0 = t * 64;

    // issue K stage for t+1 (into the buffer not being read this tile)
    if (t < 31) {
      int jn = j0 + 64;
      char* kd = Ksb + nxt * 16384;
#pragma unroll
      for (int c = 0; c < 4; ++c) {
        int ck = w * 4 + c;
        int krow = ck * 4 + kst_row;
        gload16(Kg + (size_t)(jn + krow) * 256 + (kst_x ^ ((krow & 7) << 4)), kd + ck * 1024);
      }
    }
    const char* kq = Ksb + cur * 16384 + q * 256;

    // ---- S^T = K . Q^T (two 32x32 k-halves, 8 d-steps) ----
    f32x16 s0 = {}, s1 = {};
    __builtin_amdgcn_s_setprio(1);
#pragma unroll
    for (int ds = 0; ds < 8; ++ds) {
      short8 kf0 = *(const short8*)(kq + foff[ds]);
      short8 kf1 = *(const short8*)(kq + foff[ds] + 8192);
      s0 = __builtin_amdgcn_mfma_f32_32x32x16_bf16(kf0, qf[ds], s0, 0, 0, 0);
      s1 = __builtin_amdgcn_mfma_f32_32x32x16_bf16(kf1, qf[ds], s1, 0, 0, 0);
    }
    __builtin_amdgcn_s_setprio(0);

    // ---- mask add (mask2 pre-scaled by RLN2): s*[4c+r] is k = kh*32+4*hi+r+8*c ----
#pragma unroll
    for (int c = 0; c < 4; ++c) {
      f32x4 mv0 = *(const f32x4*)(maskb + j0 + 8 * c + 4 * hi);
      f32x4 mv1 = *(const f32x4*)(maskb + j0 + 32 + 8 * c + 4 * hi);
#pragma unroll
      for (int r = 0; r < 4; ++r) {
        s0[4 * c + r] += mv0[r];
        s1[4 * c + r] += mv1[r];
      }
    }

    // ---- online softmax (balanced trees; lane owns q; reduce across hi xor 32) ----
    {
      f32x16 mx;
#pragma unroll
      for (int i = 0; i < 16; ++i) mx[i] = fmaxf(s0[i], s1[i]);
#pragma unroll
      for (int i = 0; i < 8; ++i) mx[i] = fmaxf(mx[i], mx[i + 8]);
#pragma unroll
      for (int i = 0; i < 4; ++i) mx[i] = fmaxf(mx[i], mx[i + 4]);
      float tm = fmaxf(fmaxf(mx[0], mx[1]), fmaxf(mx[2], mx[3]));
      tm = fmaxf(tm, __shfl_xor(tm, 32));

      if (__any(tm > m_run + 8.0f)) {  // defer-max (T13)
        float mn = fmaxf(m_run, tm);
        float alpha = fast_exp2(m_run - mn);
        m_run = mn;
        l_run *= alpha;
#pragma unroll
        for (int i = 0; i < 16; ++i) { accO[0][i] *= alpha; accO[1][i] *= alpha; }
      }
    }
    {
      f32x16 es;
#pragma unroll
      for (int i = 0; i < 16; ++i) {
        float e0 = fast_exp2(s0[i] - m_run);
        float e1 = fast_exp2(s1[i] - m_run);
        s0[i] = e0; s1[i] = e1;
        es[i] = e0 + e1;
      }
#pragma unroll
      for (int i = 0; i < 8; ++i) es[i] += es[i + 8];
#pragma unroll
      for (int i = 0; i < 4; ++i) es[i] += es[i + 4];
      float ps = (es[0] + es[1]) + (es[2] + es[3]);
      ps += __shfl_xor(ps, 32);
      l_run += ps;
    }

    // ---- pack P: B-frag for k-step ks = regs e+8*(ks&1) of s[ks>>1] ----
    uint4v pk[4];
#pragma unroll
    for (int ks = 0; ks < 4; ++ks) {
      int o = 8 * (ks & 1);
      const f32x16& sv = (ks < 2) ? s0 : s1;
      pk[ks][0] = cvt_pk_bf16(sv[o + 0], sv[o + 1]);
      pk[ks][1] = cvt_pk_bf16(sv[o + 2], sv[o + 3]);
      pk[ks][2] = cvt_pk_bf16(sv[o + 4], sv[o + 5]);
      pk[ks][3] = cvt_pk_bf16(sv[o + 6], sv[o + 7]);
    }

    __syncthreads();  // B1: V(t) staging (prev tail) + K(t+1) staging drained

    // ---- O += Vt-frag . P  (4 k-steps x 2 dv-halves) ----
    const char* vq = Vsb + q * 128;
    __builtin_amdgcn_s_setprio(1);
#pragma unroll
    for (int ks = 0; ks < 4; ++ks) {
      short8 pf = __builtin_bit_cast(short8, pk[ks]);
      short8 vf0 = *(const short8*)(vq + foff[ks]);
      short8 vf1 = *(const short8*)(vq + foff[ks] + 4096);
      accO[0] = __builtin_amdgcn_mfma_f32_32x32x16_bf16(vf0, pf, accO[0], 0, 0, 0);
      accO[1] = __builtin_amdgcn_mfma_f32_32x32x16_bf16(vf1, pf, accO[1], 0, 0, 0);
    }
    __builtin_amdgcn_s_setprio(0);

    __syncthreads();  // B2: all waves done reading Vsb -> safe to overwrite

    // issue V stage for t+1 (drains at next iteration's B1)
    if (t < 31) {
      int jn = j0 + 64;
#pragma unroll
      for (int c = 0; c < 2; ++c) {
        int ck = w * 2 + c;
        int dv = ck * 8 + vst_dv;
        gload16(Vg + (size_t)dv * 4096 + jn * 2 + vst_x, Vsb + ck * 1024);
      }
    }
  }

  float inv = 1.0f / l_run;
  float* orow = out + ((size_t)b_ * 2048 + i0 + w * 32 + q) * 1024 + h * 64;
#pragma unroll
  for (int vh = 0; vh < 2; ++vh) {
#pragma unroll
    for (int c = 0; c < 4; ++c) {
      f32x4 o;
      o[0] = accO[vh][4 * c + 0] * inv;
      o[1] = accO[vh][4 * c + 1] * inv;
      o[2] = accO[vh][4 * c + 2] * inv;
      o[3] = accO[vh][4 * c + 3] * inv;
      *(f32x4*)(orow + vh * 32 + 8 * c + 4 * hi) = o;
    }
  }
}

extern "C" void kernel_launch(void* const* d_in, const int* in_sizes, int n_in,
                              void* d_out, int out_size, void* d_ws, size_t ws_size,
                              hipStream_t stream) {
  (void)in_sizes; (void)n_in; (void)out_size; (void)ws_size;
  const float* hs        = (const float*)d_in[0];
  const float* mask      = (const float*)d_in[1];
  const int*   seg_ids   = (const int*)d_in[2];
  const float* Wq        = (const float*)d_in[3];
  const float* bq        = (const float*)d_in[4];
  const float* Wk        = (const float*)d_in[5];
  const float* Wv        = (const float*)d_in[6];
  const float* bv        = (const float*)d_in[7];
  const float* seg_table = (const float*)d_in[8];
  const float* bqs       = (const float*)d_in[9];
  float* out = (float*)d_out;
  char* ws = (char*)d_ws;

  unsigned short* hsb  = (unsigned short*)(ws + 0);         // 16 MiB (dead after gemm)
  unsigned short* Wcat = (unsigned short*)(ws + 16777216);  // 6 MiB
  unsigned short* Qaug = (unsigned short*)(ws + 23068672);  // 32 MiB
  unsigned short* Kaug = (unsigned short*)(ws + 56623104);  // 32 MiB
  unsigned short* Vt   = (unsigned short*)(ws + 90177536);  // 16 MiB (permuted-transposed, from gemm)
  float*          mask2 = (float*)(ws + 0);                 // 32 KiB, overlays dead hsb

  k_cvt_hs<<<dim3(4096), dim3(256), 0, stream>>>(hs, hsb);
  k_cvt_w<<<dim3(1536), dim3(256), 0, stream>>>(Wq, Wk, Wv, Wcat);
  k_gemm<<<dim3(24, 64), dim3(256), 0, stream>>>(hsb, Wcat, bq, bv, bqs, Qaug, Kaug, Vt);
  k_seg<<<dim3(4096), dim3(256), 0, stream>>>(seg_ids, seg_table, mask, Kaug, mask2);
  k_attn<<<dim3(16, 16, 4), dim3(256), 0, stream>>>(Qaug, Kaug, Vt, mask2, out);
}

// Round 9
// 275.959 us; speedup vs baseline: 1.9901x; 1.2083x over previous
//
#include <hip/hip_runtime.h>
#include <cstdint>
#include <cmath>

#define RLN2 1.44269504088896340736f

typedef __attribute__((ext_vector_type(8))) short short8;
typedef __attribute__((ext_vector_type(4))) short short4v;
typedef __attribute__((ext_vector_type(4))) float f32x4;
typedef __attribute__((ext_vector_type(16))) float f32x16;
typedef __attribute__((ext_vector_type(4))) unsigned int uint4v;

__device__ __forceinline__ unsigned short f2bf(float f) {
  unsigned int u = __float_as_uint(f);
  u += 0x7fffu + ((u >> 16) & 1u);
  return (unsigned short)(u >> 16);
}

__device__ __forceinline__ unsigned int cvt_pk_bf16(float lo, float hi) {
  unsigned int r;
  asm("v_cvt_pk_bf16_f32 %0, %1, %2" : "=v"(r) : "v"(lo), "v"(hi));
  return r;
}

__device__ __forceinline__ float fast_exp2(float x) {
#if __has_builtin(__builtin_amdgcn_exp2f)
  return __builtin_amdgcn_exp2f(x);
#else
  return exp2f(x);
#endif
}

__device__ __forceinline__ void gload16(const void* g, void* l) {
  __builtin_amdgcn_global_load_lds(
      (const __attribute__((address_space(1))) unsigned int*)g,
      (__attribute__((address_space(3))) unsigned int*)l,
      16, 0, 0);
}

// ---------------- fp32 -> bf16 conversions ----------------

__global__ void __launch_bounds__(256) k_cvt_hs(const float* __restrict__ src,
                                                unsigned short* __restrict__ dst) {
  size_t i = (size_t)blockIdx.x * 256 + threadIdx.x;
  const float4* s = (const float4*)src + i * 2;
  float4 a = s[0], b = s[1];
  short8 o;
  o[0] = (short)f2bf(a.x); o[1] = (short)f2bf(a.y); o[2] = (short)f2bf(a.z); o[3] = (short)f2bf(a.w);
  o[4] = (short)f2bf(b.x); o[5] = (short)f2bf(b.y); o[6] = (short)f2bf(b.z); o[7] = (short)f2bf(b.w);
  ((short8*)dst)[i] = o;
}

__global__ void __launch_bounds__(256) k_cvt_w(const float* __restrict__ Wq,
                                               const float* __restrict__ Wk,
                                               const float* __restrict__ Wv,
                                               unsigned short* __restrict__ dst) {
  size_t i = (size_t)blockIdx.x * 256 + threadIdx.x;
  int e = (int)(i * 8);
  int n = e >> 10, c = e & 1023;
  const float* row = (n < 1024) ? (Wq + (size_t)n * 1024)
                   : (n < 2048) ? (Wk + (size_t)(n - 1024) * 1024)
                                : (Wv + (size_t)(n - 2048) * 1024);
  const float4* s = (const float4*)(row + c);
  float4 a = s[0], b = s[1];
  short8 o;
  o[0] = (short)f2bf(a.x); o[1] = (short)f2bf(a.y); o[2] = (short)f2bf(a.z); o[3] = (short)f2bf(a.w);
  o[4] = (short)f2bf(b.x); o[5] = (short)f2bf(b.y); o[6] = (short)f2bf(b.z); o[7] = (short)f2bf(b.w);
  ((short8*)dst)[i] = o;
}

// fills Kaug second half + precomputes mask2 = mask * RLN2
__global__ void __launch_bounds__(256) k_seg(const int* __restrict__ seg_ids,
                                             const float* __restrict__ seg_table,
                                             const float* __restrict__ mask,
                                             unsigned short* __restrict__ Kaug,
                                             float* __restrict__ mask2) {
  size_t i = (size_t)blockIdx.x * 256 + threadIdx.x;
  int e = (int)(i * 8);
  int jl = e >> 10;
  int r  = e & 1023;
  if (r == 0) mask2[jl] = mask[jl] * RLN2;
  int sid = seg_ids[jl];
  const float4* s = (const float4*)(seg_table + (size_t)sid * 1024 + r);
  float4 a = s[0], b = s[1];
  short8 o;
  o[0] = (short)f2bf(a.x); o[1] = (short)f2bf(a.y); o[2] = (short)f2bf(a.z); o[3] = (short)f2bf(a.w);
  o[4] = (short)f2bf(b.x); o[5] = (short)f2bf(b.y); o[6] = (short)f2bf(b.z); o[7] = (short)f2bf(b.w);
  int b_ = jl >> 11, j = jl & 2047;
  int h = r >> 6, d = r & 63;
  size_t off = ((size_t)(b_ * 16 + h) * 2048 + j) * 128 + 64 + d;
  *(short8*)(Kaug + off) = o;
}

// ---------------- fused QKV GEMM (NT) ----------------
// epilogue: Q -> Qaug (scaled halves), K -> Kaug first half,
// V -> Vt DIRECTLY: [bh][64 dv][2048 pos] with the PV k-permutation folded in:
//   k = sdx&63 = m*16 + g*4 + r -> pos = (sdx&~63) + 32*((m>>1)&1) + 16*(m&1) + 8*(g&1) + 4*((g>>1)&1) + r
__global__ void __launch_bounds__(256) k_gemm(const unsigned short* __restrict__ A,
                                              const unsigned short* __restrict__ Bw,
                                              const float* __restrict__ bq,
                                              const float* __restrict__ bv,
                                              const float* __restrict__ bqs,
                                              unsigned short* __restrict__ Qaug,
                                              unsigned short* __restrict__ Kaug,
                                              unsigned short* __restrict__ Vt) {
  __shared__ unsigned short As[128 * 32];
  __shared__ unsigned short Bs[128 * 32];
  int n0 = blockIdx.x * 128;
  int m0 = blockIdx.y * 128;
  int tid = threadIdx.x;
  int w = tid >> 6, lane = tid & 63;
  int wr = (w >> 1) * 64, wc = (w & 1) * 64;
  int rA = lane & 15;
  int kg = (lane >> 4) * 16;
  f32x4 acc[4][4] = {};
  const char* Ab = (const char*)A;
  const char* Bb = (const char*)Bw;

  for (int kt = 0; kt < 32; ++kt) {
    int kb0 = kt * 64;
#pragma unroll
    for (int c = 0; c < 2; ++c) {
      int chunk = w * 2 + c;
      int y = chunk * 1024 + lane * 16;
      int row = y >> 6, colb = y & 63;
      gload16(Ab + (size_t)(m0 + row) * 2048 + kb0 + colb, (char*)As + chunk * 1024);
      gload16(Bb + (size_t)(n0 + row) * 2048 + kb0 + colb, (char*)Bs + chunk * 1024);
    }
    __syncthreads();
    short8 af[4], bfr[4];
#pragma unroll
    for (int m = 0; m < 4; ++m)
      af[m] = *(const short8*)((const char*)As + (wr + m * 16 + rA) * 64 + kg);
#pragma unroll
    for (int n = 0; n < 4; ++n)
      bfr[n] = *(const short8*)((const char*)Bs + (wc + n * 16 + rA) * 64 + kg);
#pragma unroll
    for (int m = 0; m < 4; ++m)
#pragma unroll
      for (int n = 0; n < 4; ++n)
        acc[m][n] = __builtin_amdgcn_mfma_f32_16x16x32_bf16(af[m], bfr[n], acc[m][n], 0, 0, 0);
    __syncthreads();
  }

  int seg = n0 >> 10;
  int colbase = n0 & 1023;
  int g = lane >> 4;
#pragma unroll
  for (int n = 0; n < 4; ++n) {
    int o = colbase + wc + n * 16 + (lane & 15);
    int h = o >> 6, d = o & 63;
    float bias = 0.f, bqsv = 0.f;
    if (seg == 0) { bias = bq[o]; bqsv = bqs[o]; }
    else if (seg == 2) { bias = bv[o]; }
#pragma unroll
    for (int m = 0; m < 4; ++m) {
      if (seg == 2) {
        int i = m0 + wr + m * 16 + g * 4;  // r=0 token
        int b_ = i >> 11, sdx = i & 2047;
        int bh = b_ * 16 + h;
        int pos = (sdx & ~63) + 32 * ((m >> 1) & 1) + 16 * (m & 1) + 8 * (g & 1) + 4 * ((g >> 1) & 1);
        short4v pv;
#pragma unroll
        for (int r = 0; r < 4; ++r)
          pv[r] = (short)f2bf(acc[m][n][r] + bias);
        *(short4v*)(Vt + (size_t)bh * 131072 + (size_t)d * 2048 + pos) = pv;
      } else {
#pragma unroll
        for (int r = 0; r < 4; ++r) {
          int i = m0 + wr + m * 16 + g * 4 + r;
          int b_ = i >> 11, sdx = i & 2047;
          float val = acc[m][n][r];
          size_t tok = (size_t)(b_ * 16 + h) * 2048 + sdx;
          if (seg == 0) {
            float qv = val + bias;
            Qaug[tok * 128 + d]      = f2bf(qv * (0.125f * RLN2));
            Qaug[tok * 128 + 64 + d] = f2bf((qv + bqsv) * RLN2);
          } else {
            Kaug[tok * 128 + d] = f2bf(val);
          }
        }
      }
    }
  }
}

// ---------------- flash attention, 32x32x16 MFMA, 32 q-rows/wave ----------------
// R3's proven structure verbatim: K 2x16K + V 2x8K double-buffered (48KB),
// prefetch t+1 at tile start, ONE __syncthreads per tile at the end.
// Only local tweaks: mask2 pre-scaled (no per-tile RLN2 mul), balanced-tree reduce.
__global__ void __launch_bounds__(256, 3) k_attn(const unsigned short* __restrict__ Qaug,
                                                 const unsigned short* __restrict__ Kaug,
                                                 const unsigned short* __restrict__ Vt,
                                                 const float* __restrict__ mask2,
                                                 float* __restrict__ out) {
  __shared__ char smem[49152];
  char* Ksb = smem;          // 2 x 16K
  char* Vsb = smem + 32768;  // 2 x 8K

  int qt = blockIdx.x, h = blockIdx.y, b_ = blockIdx.z;
  int bh = b_ * 16 + h;
  int i0 = qt * 128;
  int tid = threadIdx.x, w = tid >> 6, lane = tid & 63;
  int q = lane & 31, hi = lane >> 5;
  int swzq = (q & 7) << 4;
  const char* Qg = (const char*)Qaug + (size_t)bh * 2048 * 256;
  const char* Kg = (const char*)Kaug + (size_t)bh * 2048 * 256;
  const char* Vg = (const char*)Vt + (size_t)bh * 64 * 4096;
  const float* maskb = mask2 + (size_t)b_ * 2048;

  // tile-invariant fragment byte offsets (within a K row / V row)
  int foff[8];
#pragma unroll
  for (int ds = 0; ds < 8; ++ds)
    foff[ds] = (ds * 32 + hi * 16) ^ swzq;

  // staging lane decomps
  int kst_row = lane >> 4, kst_x = (lane & 15) * 16;
  int vst_dv = lane >> 3;
  int vst_x = ((lane & 7) * 16) ^ ((vst_dv & 7) << 4);

  // ---- stage tile 0 ----
#pragma unroll
  for (int c = 0; c < 4; ++c) {
    int ck = w * 4 + c;
    int krow = ck * 4 + kst_row;
    gload16(Kg + (size_t)krow * 256 + (kst_x ^ ((krow & 7) << 4)), Ksb + ck * 1024);
  }
#pragma unroll
  for (int c = 0; c < 2; ++c) {
    int ck = w * 2 + c;
    int dv = ck * 8 + vst_dv;
    gload16(Vg + (size_t)dv * 4096 + vst_x, Vsb + ck * 1024);
  }

  // Q fragments (B-operand): row = i0 + w*32 + q, 8 x 16B at ds*32 + hi*16
  short8 qf[8];
  {
    const char* qrow = Qg + (size_t)(i0 + w * 32 + q) * 256 + hi * 16;
#pragma unroll
    for (int ds = 0; ds < 8; ++ds)
      qf[ds] = *(const short8*)(qrow + ds * 32);
  }
  __syncthreads();  // K0/V0 resident

  float m_run = -1e30f, l_run = 0.f;
  f32x16 accO[2] = {};

  for (int t = 0; t < 32; ++t) {
    int cur = t & 1, nxt = cur ^ 1;
    int j0 = t * 64;
    if (t < 31) {  // prefetch t+1 into the other buffers (drains at end-of-tile barrier)
      int jn = j0 + 64;
      char* kd = Ksb + nxt * 16384;
      char* vd = Vsb + nxt * 8192;
#pragma unroll
      for (int c = 0; c < 4; ++c) {
        int ck = w * 4 + c;
        int krow = ck * 4 + kst_row;
        gload16(Kg + (size_t)(jn + krow) * 256 + (kst_x ^ ((krow & 7) << 4)), kd + ck * 1024);
      }
#pragma unroll
      for (int c = 0; c < 2; ++c) {
        int ck = w * 2 + c;
        int dv = ck * 8 + vst_dv;
        gload16(Vg + (size_t)dv * 4096 + jn * 2 + vst_x, vd + ck * 1024);
      }
    }
    const char* kq = Ksb + cur * 16384 + q * 256;
    const char* vq = Vsb + cur * 8192 + q * 128;

    // ---- S^T = K . Q^T (two 32x32 k-halves, 8 d-steps) ----
    f32x16 s0 = {}, s1 = {};
    __builtin_amdgcn_s_setprio(1);
#pragma unroll
    for (int ds = 0; ds < 8; ++ds) {
      short8 kf0 = *(const short8*)(kq + foff[ds]);
      short8 kf1 = *(const short8*)(kq + foff[ds] + 8192);
      s0 = __builtin_amdgcn_mfma_f32_32x32x16_bf16(kf0, qf[ds], s0, 0, 0, 0);
      s1 = __builtin_amdgcn_mfma_f32_32x32x16_bf16(kf1, qf[ds], s1, 0, 0, 0);
    }
    __builtin_amdgcn_s_setprio(0);

    // ---- mask add (mask2 pre-scaled): s*[4c+r] is k = kh*32 + 4*hi + r + 8*c ----
#pragma unroll
    for (int c = 0; c < 4; ++c) {
      f32x4 mv0 = *(const f32x4*)(maskb + j0 + 8 * c + 4 * hi);
      f32x4 mv1 = *(const f32x4*)(maskb + j0 + 32 + 8 * c + 4 * hi);
#pragma unroll
      for (int r = 0; r < 4; ++r) {
        s0[4 * c + r] += mv0[r];
        s1[4 * c + r] += mv1[r];
      }
    }

    // ---- online softmax (balanced trees; lane owns q; reduce across hi xor 32) ----
    {
      f32x16 mx;
#pragma unroll
      for (int i = 0; i < 16; ++i) mx[i] = fmaxf(s0[i], s1[i]);
#pragma unroll
      for (int i = 0; i < 8; ++i) mx[i] = fmaxf(mx[i], mx[i + 8]);
#pragma unroll
      for (int i = 0; i < 4; ++i) mx[i] = fmaxf(mx[i], mx[i + 4]);
      float tm = fmaxf(fmaxf(mx[0], mx[1]), fmaxf(mx[2], mx[3]));
      tm = fmaxf(tm, __shfl_xor(tm, 32));

      if (__any(tm > m_run + 8.0f)) {  // defer-max (T13)
        float mn = fmaxf(m_run, tm);
        float alpha = fast_exp2(m_run - mn);
        m_run = mn;
        l_run *= alpha;
#pragma unroll
        for (int i = 0; i < 16; ++i) { accO[0][i] *= alpha; accO[1][i] *= alpha; }
      }
    }
    {
      f32x16 es;
#pragma unroll
      for (int i = 0; i < 16; ++i) {
        float e0 = fast_exp2(s0[i] - m_run);
        float e1 = fast_exp2(s1[i] - m_run);
        s0[i] = e0; s1[i] = e1;
        es[i] = e0 + e1;
      }
#pragma unroll
      for (int i = 0; i < 8; ++i) es[i] += es[i + 8];
#pragma unroll
      for (int i = 0; i < 4; ++i) es[i] += es[i + 4];
      float ps = (es[0] + es[1]) + (es[2] + es[3]);
      ps += __shfl_xor(ps, 32);
      l_run += ps;
    }

    // ---- pack P: B-frag for k-step ks = regs e+8*(ks&1) of s[ks>>1] ----
    uint4v pk[4];
#pragma unroll
    for (int ks = 0; ks < 4; ++ks) {
      int o = 8 * (ks & 1);
      const f32x16& sv = (ks < 2) ? s0 : s1;
      pk[ks][0] = cvt_pk_bf16(sv[o + 0], sv[o + 1]);
      pk[ks][1] = cvt_pk_bf16(sv[o + 2], sv[o + 3]);
      pk[ks][2] = cvt_pk_bf16(sv[o + 4], sv[o + 5]);
      pk[ks][3] = cvt_pk_bf16(sv[o + 6], sv[o + 7]);
    }

    // ---- O += Vt-frag . P  (4 k-steps x 2 dv-halves) ----
    __builtin_amdgcn_s_setprio(1);
#pragma unroll
    for (int ks = 0; ks < 4; ++ks) {
      short8 pf = __builtin_bit_cast(short8, pk[ks]);
      short8 vf0 = *(const short8*)(vq + foff[ks]);
      short8 vf1 = *(const short8*)(vq + foff[ks] + 4096);
      accO[0] = __builtin_amdgcn_mfma_f32_32x32x16_bf16(vf0, pf, accO[0], 0, 0, 0);
      accO[1] = __builtin_amdgcn_mfma_f32_32x32x16_bf16(vf1, pf, accO[1], 0, 0, 0);
    }
    __builtin_amdgcn_s_setprio(0);
    __syncthreads();  // single barrier: prefetch drained; buffers swap
  }

  float inv = 1.0f / l_run;
  float* orow = out + ((size_t)b_ * 2048 + i0 + w * 32 + q) * 1024 + h * 64;
#pragma unroll
  for (int vh = 0; vh < 2; ++vh) {
#pragma unroll
    for (int c = 0; c < 4; ++c) {
      f32x4 o;
      o[0] = accO[vh][4 * c + 0] * inv;
      o[1] = accO[vh][4 * c + 1] * inv;
      o[2] = accO[vh][4 * c + 2] * inv;
      o[3] = accO[vh][4 * c + 3] * inv;
      *(f32x4*)(orow + vh * 32 + 8 * c + 4 * hi) = o;
    }
  }
}

extern "C" void kernel_launch(void* const* d_in, const int* in_sizes, int n_in,
                              void* d_out, int out_size, void* d_ws, size_t ws_size,
                              hipStream_t stream) {
  (void)in_sizes; (void)n_in; (void)out_size; (void)ws_size;
  const float* hs        = (const float*)d_in[0];
  const float* mask      = (const float*)d_in[1];
  const int*   seg_ids   = (const int*)d_in[2];
  const float* Wq        = (const float*)d_in[3];
  const float* bq        = (const float*)d_in[4];
  const float* Wk        = (const float*)d_in[5];
  const float* Wv        = (const float*)d_in[6];
  const float* bv        = (const float*)d_in[7];
  const float* seg_table = (const float*)d_in[8];
  const float* bqs       = (const float*)d_in[9];
  float* out = (float*)d_out;
  char* ws = (char*)d_ws;

  unsigned short* hsb  = (unsigned short*)(ws + 0);         // 16 MiB (dead after gemm)
  unsigned short* Wcat = (unsigned short*)(ws + 16777216);  // 6 MiB
  unsigned short* Qaug = (unsigned short*)(ws + 23068672);  // 32 MiB
  unsigned short* Kaug = (unsigned short*)(ws + 56623104);  // 32 MiB
  unsigned short* Vt   = (unsigned short*)(ws + 90177536);  // 16 MiB (permuted-transposed, from gemm)
  float*          mask2 = (float*)(ws + 0);                 // 32 KiB, overlays dead hsb

  k_cvt_hs<<<dim3(4096), dim3(256), 0, stream>>>(hs, hsb);
  k_cvt_w<<<dim3(1536), dim3(256), 0, stream>>>(Wq, Wk, Wv, Wcat);
  k_gemm<<<dim3(24, 64), dim3(256), 0, stream>>>(hsb, Wcat, bq, bv, bqs, Qaug, Kaug, Vt);
  k_seg<<<dim3(4096), dim3(256), 0, stream>>>(seg_ids, seg_table, mask, Kaug, mask2);
  k_attn<<<dim3(16, 16, 4), dim3(256), 0, stream>>>(Qaug, Kaug, Vt, mask2, out);
}

// Round 10
// 267.756 us; speedup vs baseline: 2.0510x; 1.0306x over previous
//
#include <hip/hip_runtime.h>
#include <cstdint>
#include <cmath>

#define RLN2 1.44269504088896340736f

typedef __attribute__((ext_vector_type(8))) short short8;
typedef __attribute__((ext_vector_type(4))) short short4v;
typedef __attribute__((ext_vector_type(4))) float f32x4;
typedef __attribute__((ext_vector_type(16))) float f32x16;
typedef __attribute__((ext_vector_type(4))) unsigned int uint4v;

__device__ __forceinline__ unsigned short f2bf(float f) {
  unsigned int u = __float_as_uint(f);
  u += 0x7fffu + ((u >> 16) & 1u);
  return (unsigned short)(u >> 16);
}

__device__ __forceinline__ unsigned int cvt_pk_bf16(float lo, float hi) {
  unsigned int r;
  asm("v_cvt_pk_bf16_f32 %0, %1, %2" : "=v"(r) : "v"(lo), "v"(hi));
  return r;
}

__device__ __forceinline__ float fast_exp2(float x) {
#if __has_builtin(__builtin_amdgcn_exp2f)
  return __builtin_amdgcn_exp2f(x);
#else
  return exp2f(x);
#endif
}

__device__ __forceinline__ void gload16(const void* g, void* l) {
  __builtin_amdgcn_global_load_lds(
      (const __attribute__((address_space(1))) unsigned int*)g,
      (__attribute__((address_space(3))) unsigned int*)l,
      16, 0, 0);
}

// ---------------- fp32 -> bf16 conversions ----------------

__global__ void __launch_bounds__(256) k_cvt_hs(const float* __restrict__ src,
                                                unsigned short* __restrict__ dst) {
  size_t i = (size_t)blockIdx.x * 256 + threadIdx.x;
  const float4* s = (const float4*)src + i * 2;
  float4 a = s[0], b = s[1];
  short8 o;
  o[0] = (short)f2bf(a.x); o[1] = (short)f2bf(a.y); o[2] = (short)f2bf(a.z); o[3] = (short)f2bf(a.w);
  o[4] = (short)f2bf(b.x); o[5] = (short)f2bf(b.y); o[6] = (short)f2bf(b.z); o[7] = (short)f2bf(b.w);
  ((short8*)dst)[i] = o;
}

__global__ void __launch_bounds__(256) k_cvt_w(const float* __restrict__ Wq,
                                               const float* __restrict__ Wk,
                                               const float* __restrict__ Wv,
                                               unsigned short* __restrict__ dst) {
  size_t i = (size_t)blockIdx.x * 256 + threadIdx.x;
  int e = (int)(i * 8);
  int n = e >> 10, c = e & 1023;
  const float* row = (n < 1024) ? (Wq + (size_t)n * 1024)
                   : (n < 2048) ? (Wk + (size_t)(n - 1024) * 1024)
                                : (Wv + (size_t)(n - 2048) * 1024);
  const float4* s = (const float4*)(row + c);
  float4 a = s[0], b = s[1];
  short8 o;
  o[0] = (short)f2bf(a.x); o[1] = (short)f2bf(a.y); o[2] = (short)f2bf(a.z); o[3] = (short)f2bf(a.w);
  o[4] = (short)f2bf(b.x); o[5] = (short)f2bf(b.y); o[6] = (short)f2bf(b.z); o[7] = (short)f2bf(b.w);
  ((short8*)dst)[i] = o;
}

// fills Kaug second half + precomputes mask2 = mask * RLN2
__global__ void __launch_bounds__(256) k_seg(const int* __restrict__ seg_ids,
                                             const float* __restrict__ seg_table,
                                             const float* __restrict__ mask,
                                             unsigned short* __restrict__ Kaug,
                                             float* __restrict__ mask2) {
  size_t i = (size_t)blockIdx.x * 256 + threadIdx.x;
  int e = (int)(i * 8);
  int jl = e >> 10;
  int r  = e & 1023;
  if (r == 0) mask2[jl] = mask[jl] * RLN2;
  int sid = seg_ids[jl];
  const float4* s = (const float4*)(seg_table + (size_t)sid * 1024 + r);
  float4 a = s[0], b = s[1];
  short8 o;
  o[0] = (short)f2bf(a.x); o[1] = (short)f2bf(a.y); o[2] = (short)f2bf(a.z); o[3] = (short)f2bf(a.w);
  o[4] = (short)f2bf(b.x); o[5] = (short)f2bf(b.y); o[6] = (short)f2bf(b.z); o[7] = (short)f2bf(b.w);
  int b_ = jl >> 11, j = jl & 2047;
  int h = r >> 6, d = r & 63;
  size_t off = ((size_t)(b_ * 16 + h) * 2048 + j) * 128 + 64 + d;
  *(short8*)(Kaug + off) = o;
}

// ---------------- fused QKV GEMM (NT) ----------------
// epilogue: Q -> Qaug (scaled halves), K -> Kaug first half,
// V -> Vt DIRECTLY: [bh][64 dv][2048 pos] with the PV k-permutation folded in:
//   k = sdx&63 = m*16 + g*4 + r -> pos = (sdx&~63) + 32*((m>>1)&1) + 16*(m&1) + 8*(g&1) + 4*((g>>1)&1) + r
__global__ void __launch_bounds__(256) k_gemm(const unsigned short* __restrict__ A,
                                              const unsigned short* __restrict__ Bw,
                                              const float* __restrict__ bq,
                                              const float* __restrict__ bv,
                                              const float* __restrict__ bqs,
                                              unsigned short* __restrict__ Qaug,
                                              unsigned short* __restrict__ Kaug,
                                              unsigned short* __restrict__ Vt) {
  __shared__ unsigned short As[128 * 32];
  __shared__ unsigned short Bs[128 * 32];
  int n0 = blockIdx.x * 128;
  int m0 = blockIdx.y * 128;
  int tid = threadIdx.x;
  int w = tid >> 6, lane = tid & 63;
  int wr = (w >> 1) * 64, wc = (w & 1) * 64;
  int rA = lane & 15;
  int kg = (lane >> 4) * 16;
  f32x4 acc[4][4] = {};
  const char* Ab = (const char*)A;
  const char* Bb = (const char*)Bw;

  for (int kt = 0; kt < 32; ++kt) {
    int kb0 = kt * 64;
#pragma unroll
    for (int c = 0; c < 2; ++c) {
      int chunk = w * 2 + c;
      int y = chunk * 1024 + lane * 16;
      int row = y >> 6, colb = y & 63;
      gload16(Ab + (size_t)(m0 + row) * 2048 + kb0 + colb, (char*)As + chunk * 1024);
      gload16(Bb + (size_t)(n0 + row) * 2048 + kb0 + colb, (char*)Bs + chunk * 1024);
    }
    __syncthreads();
    short8 af[4], bfr[4];
#pragma unroll
    for (int m = 0; m < 4; ++m)
      af[m] = *(const short8*)((const char*)As + (wr + m * 16 + rA) * 64 + kg);
#pragma unroll
    for (int n = 0; n < 4; ++n)
      bfr[n] = *(const short8*)((const char*)Bs + (wc + n * 16 + rA) * 64 + kg);
#pragma unroll
    for (int m = 0; m < 4; ++m)
#pragma unroll
      for (int n = 0; n < 4; ++n)
        acc[m][n] = __builtin_amdgcn_mfma_f32_16x16x32_bf16(af[m], bfr[n], acc[m][n], 0, 0, 0);
    __syncthreads();
  }

  int seg = n0 >> 10;
  int colbase = n0 & 1023;
  int g = lane >> 4;
#pragma unroll
  for (int n = 0; n < 4; ++n) {
    int o = colbase + wc + n * 16 + (lane & 15);
    int h = o >> 6, d = o & 63;
    float bias = 0.f, bqsv = 0.f;
    if (seg == 0) { bias = bq[o]; bqsv = bqs[o]; }
    else if (seg == 2) { bias = bv[o]; }
#pragma unroll
    for (int m = 0; m < 4; ++m) {
      if (seg == 2) {
        int i = m0 + wr + m * 16 + g * 4;  // r=0 token
        int b_ = i >> 11, sdx = i & 2047;
        int bh = b_ * 16 + h;
        int pos = (sdx & ~63) + 32 * ((m >> 1) & 1) + 16 * (m & 1) + 8 * (g & 1) + 4 * ((g >> 1) & 1);
        short4v pv;
#pragma unroll
        for (int r = 0; r < 4; ++r)
          pv[r] = (short)f2bf(acc[m][n][r] + bias);
        *(short4v*)(Vt + (size_t)bh * 131072 + (size_t)d * 2048 + pos) = pv;
      } else {
#pragma unroll
        for (int r = 0; r < 4; ++r) {
          int i = m0 + wr + m * 16 + g * 4 + r;
          int b_ = i >> 11, sdx = i & 2047;
          float val = acc[m][n][r];
          size_t tok = (size_t)(b_ * 16 + h) * 2048 + sdx;
          if (seg == 0) {
            float qv = val + bias;
            Qaug[tok * 128 + d]      = f2bf(qv * (0.125f * RLN2));
            Qaug[tok * 128 + 64 + d] = f2bf((qv + bqsv) * RLN2);
          } else {
            Kaug[tok * 128 + d] = f2bf(val);
          }
        }
      }
    }
  }
}

// ---------------- flash attention, 32x32x16 MFMA, 32 q-rows/wave ----------------
// R8 inner loop verbatim; block widened to 8 waves / 256 q-rows.
// Grid 512 = exactly 2 blocks/CU, fully co-resident (no tail): 16 waves/CU steady
// vs ~8 time-averaged before. K/V staged once per 256 q-rows (staging/wave halves);
// each bh's K/V stream read by 8 blocks instead of 16 (FETCH halves).
__global__ void __launch_bounds__(512, 4) k_attn(const unsigned short* __restrict__ Qaug,
                                                 const unsigned short* __restrict__ Kaug,
                                                 const unsigned short* __restrict__ Vt,
                                                 const float* __restrict__ mask2,
                                                 float* __restrict__ out) {
  __shared__ char smem[49152];
  char* Ksb = smem;          // 2 x 16K
  char* Vsb = smem + 32768;  // 2 x 8K

  int qt = blockIdx.x, h = blockIdx.y, b_ = blockIdx.z;
  int bh = b_ * 16 + h;
  int i0 = qt * 256;
  int tid = threadIdx.x, w = tid >> 6, lane = tid & 63;
  int q = lane & 31, hi = lane >> 5;
  int swzq = (q & 7) << 4;
  const char* Qg = (const char*)Qaug + (size_t)bh * 2048 * 256;
  const char* Kg = (const char*)Kaug + (size_t)bh * 2048 * 256;
  const char* Vg = (const char*)Vt + (size_t)bh * 64 * 4096;
  const float* maskb = mask2 + (size_t)b_ * 2048;

  // tile-invariant fragment byte offsets (within a K row / V row)
  int foff[8];
#pragma unroll
  for (int ds = 0; ds < 8; ++ds)
    foff[ds] = (ds * 32 + hi * 16) ^ swzq;

  // staging lane decomps (8 waves: K = 2 chunks/wave, V = 1 chunk/wave)
  int kst_row = lane >> 4, kst_x = (lane & 15) * 16;
  int vst_dv = lane >> 3;
  int vst_x = ((lane & 7) * 16) ^ ((vst_dv & 7) << 4);

  // ---- stage tile 0 ----
#pragma unroll
  for (int c = 0; c < 2; ++c) {
    int ck = w * 2 + c;
    int krow = ck * 4 + kst_row;
    gload16(Kg + (size_t)krow * 256 + (kst_x ^ ((krow & 7) << 4)), Ksb + ck * 1024);
  }
  {
    int dv = w * 8 + vst_dv;
    gload16(Vg + (size_t)dv * 4096 + vst_x, Vsb + w * 1024);
  }

  // Q fragments (B-operand): row = i0 + w*32 + q, 8 x 16B at ds*32 + hi*16
  short8 qf[8];
  {
    const char* qrow = Qg + (size_t)(i0 + w * 32 + q) * 256 + hi * 16;
#pragma unroll
    for (int ds = 0; ds < 8; ++ds)
      qf[ds] = *(const short8*)(qrow + ds * 32);
  }
  __syncthreads();  // K0/V0 resident

  float m_run = -1e30f, l_run = 0.f;
  f32x16 accO[2] = {};

  for (int t = 0; t < 32; ++t) {
    int cur = t & 1, nxt = cur ^ 1;
    int j0 = t * 64;
    if (t < 31) {  // prefetch t+1 into the other buffers (drains at end-of-tile barrier)
      int jn = j0 + 64;
      char* kd = Ksb + nxt * 16384;
      char* vd = Vsb + nxt * 8192;
#pragma unroll
      for (int c = 0; c < 2; ++c) {
        int ck = w * 2 + c;
        int krow = ck * 4 + kst_row;
        gload16(Kg + (size_t)(jn + krow) * 256 + (kst_x ^ ((krow & 7) << 4)), kd + ck * 1024);
      }
      {
        int dv = w * 8 + vst_dv;
        gload16(Vg + (size_t)dv * 4096 + jn * 2 + vst_x, vd + w * 1024);
      }
    }
    const char* kq = Ksb + cur * 16384 + q * 256;
    const char* vq = Vsb + cur * 8192 + q * 128;

    // ---- S^T = K . Q^T (two 32x32 k-halves, 8 d-steps) ----
    f32x16 s0 = {}, s1 = {};
    __builtin_amdgcn_s_setprio(1);
#pragma unroll
    for (int ds = 0; ds < 8; ++ds) {
      short8 kf0 = *(const short8*)(kq + foff[ds]);
      short8 kf1 = *(const short8*)(kq + foff[ds] + 8192);
      s0 = __builtin_amdgcn_mfma_f32_32x32x16_bf16(kf0, qf[ds], s0, 0, 0, 0);
      s1 = __builtin_amdgcn_mfma_f32_32x32x16_bf16(kf1, qf[ds], s1, 0, 0, 0);
    }
    __builtin_amdgcn_s_setprio(0);

    // ---- mask add (mask2 pre-scaled): s*[4c+r] is k = kh*32 + 4*hi + r + 8*c ----
#pragma unroll
    for (int c = 0; c < 4; ++c) {
      f32x4 mv0 = *(const f32x4*)(maskb + j0 + 8 * c + 4 * hi);
      f32x4 mv1 = *(const f32x4*)(maskb + j0 + 32 + 8 * c + 4 * hi);
#pragma unroll
      for (int r = 0; r < 4; ++r) {
        s0[4 * c + r] += mv0[r];
        s1[4 * c + r] += mv1[r];
      }
    }

    // ---- online softmax (balanced trees; lane owns q; reduce across hi xor 32) ----
    {
      f32x16 mx;
#pragma unroll
      for (int i = 0; i < 16; ++i) mx[i] = fmaxf(s0[i], s1[i]);
#pragma unroll
      for (int i = 0; i < 8; ++i) mx[i] = fmaxf(mx[i], mx[i + 8]);
#pragma unroll
      for (int i = 0; i < 4; ++i) mx[i] = fmaxf(mx[i], mx[i + 4]);
      float tm = fmaxf(fmaxf(mx[0], mx[1]), fmaxf(mx[2], mx[3]));
      tm = fmaxf(tm, __shfl_xor(tm, 32));

      if (__any(tm > m_run + 8.0f)) {  // defer-max (T13)
        float mn = fmaxf(m_run, tm);
        float alpha = fast_exp2(m_run - mn);
        m_run = mn;
        l_run *= alpha;
#pragma unroll
        for (int i = 0; i < 16; ++i) { accO[0][i] *= alpha; accO[1][i] *= alpha; }
      }
    }
    {
      f32x16 es;
#pragma unroll
      for (int i = 0; i < 16; ++i) {
        float e0 = fast_exp2(s0[i] - m_run);
        float e1 = fast_exp2(s1[i] - m_run);
        s0[i] = e0; s1[i] = e1;
        es[i] = e0 + e1;
      }
#pragma unroll
      for (int i = 0; i < 8; ++i) es[i] += es[i + 8];
#pragma unroll
      for (int i = 0; i < 4; ++i) es[i] += es[i + 4];
      float ps = (es[0] + es[1]) + (es[2] + es[3]);
      ps += __shfl_xor(ps, 32);
      l_run += ps;
    }

    // ---- pack P: B-frag for k-step ks = regs e+8*(ks&1) of s[ks>>1] ----
    uint4v pk[4];
#pragma unroll
    for (int ks = 0; ks < 4; ++ks) {
      int o = 8 * (ks & 1);
      const f32x16& sv = (ks < 2) ? s0 : s1;
      pk[ks][0] = cvt_pk_bf16(sv[o + 0], sv[o + 1]);
      pk[ks][1] = cvt_pk_bf16(sv[o + 2], sv[o + 3]);
      pk[ks][2] = cvt_pk_bf16(sv[o + 4], sv[o + 5]);
      pk[ks][3] = cvt_pk_bf16(sv[o + 6], sv[o + 7]);
    }

    // ---- O += Vt-frag . P  (4 k-steps x 2 dv-halves) ----
    __builtin_amdgcn_s_setprio(1);
#pragma unroll
    for (int ks = 0; ks < 4; ++ks) {
      short8 pf = __builtin_bit_cast(short8, pk[ks]);
      short8 vf0 = *(const short8*)(vq + foff[ks]);
      short8 vf1 = *(const short8*)(vq + foff[ks] + 4096);
      accO[0] = __builtin_amdgcn_mfma_f32_32x32x16_bf16(vf0, pf, accO[0], 0, 0, 0);
      accO[1] = __builtin_amdgcn_mfma_f32_32x32x16_bf16(vf1, pf, accO[1], 0, 0, 0);
    }
    __builtin_amdgcn_s_setprio(0);
    __syncthreads();  // single barrier: prefetch drained; buffers swap
  }

  float inv = 1.0f / l_run;
  float* orow = out + ((size_t)b_ * 2048 + i0 + w * 32 + q) * 1024 + h * 64;
#pragma unroll
  for (int vh = 0; vh < 2; ++vh) {
#pragma unroll
    for (int c = 0; c < 4; ++c) {
      f32x4 o;
      o[0] = accO[vh][4 * c + 0] * inv;
      o[1] = accO[vh][4 * c + 1] * inv;
      o[2] = accO[vh][4 * c + 2] * inv;
      o[3] = accO[vh][4 * c + 3] * inv;
      *(f32x4*)(orow + vh * 32 + 8 * c + 4 * hi) = o;
    }
  }
}

extern "C" void kernel_launch(void* const* d_in, const int* in_sizes, int n_in,
                              void* d_out, int out_size, void* d_ws, size_t ws_size,
                              hipStream_t stream) {
  (void)in_sizes; (void)n_in; (void)out_size; (void)ws_size;
  const float* hs        = (const float*)d_in[0];
  const float* mask      = (const float*)d_in[1];
  const int*   seg_ids   = (const int*)d_in[2];
  const float* Wq        = (const float*)d_in[3];
  const float* bq        = (const float*)d_in[4];
  const float* Wk        = (const float*)d_in[5];
  const float* Wv        = (const float*)d_in[6];
  const float* bv        = (const float*)d_in[7];
  const float* seg_table = (const float*)d_in[8];
  const float* bqs       = (const float*)d_in[9];
  float* out = (float*)d_out;
  char* ws = (char*)d_ws;

  unsigned short* hsb  = (unsigned short*)(ws + 0);         // 16 MiB (dead after gemm)
  unsigned short* Wcat = (unsigned short*)(ws + 16777216);  // 6 MiB
  unsigned short* Qaug = (unsigned short*)(ws + 23068672);  // 32 MiB
  unsigned short* Kaug = (unsigned short*)(ws + 56623104);  // 32 MiB
  unsigned short* Vt   = (unsigned short*)(ws + 90177536);  // 16 MiB (permuted-transposed, from gemm)
  float*          mask2 = (float*)(ws + 0);                 // 32 KiB, overlays dead hsb

  k_cvt_hs<<<dim3(4096), dim3(256), 0, stream>>>(hs, hsb);
  k_cvt_w<<<dim3(1536), dim3(256), 0, stream>>>(Wq, Wk, Wv, Wcat);
  k_gemm<<<dim3(24, 64), dim3(256), 0, stream>>>(hsb, Wcat, bq, bv, bqs, Qaug, Kaug, Vt);
  k_seg<<<dim3(4096), dim3(256), 0, stream>>>(seg_ids, seg_table, mask, Kaug, mask2);
  k_attn<<<dim3(8, 16, 4), dim3(512), 0, stream>>>(Qaug, Kaug, Vt, mask2, out);
}